// Round 10
// baseline (807.639 us; speedup 1.0000x reference)
//
#include <hip/hip_runtime.h>
#include <cmath>

// ---------------------------------------------------------------------------
// Round 15 = r14 (800us) with ALL remaining accumulator chains split.
// Since only element [0] of every accumulator is consumed (r14 duplication),
// a k-chain of dependent MFMAs can be split into two independent halves
// joined by ONE scalar add -- removes the final MFMA-latency link(s) from
// each phase's serial tail (pattern proven by the P3 f-chain in r12/r13):
//   P1: cf/cg/cr 2-dep -> 1+1 (+3 adds)
//   P2: c0/c1 4-dep -> 2+2 (+2 adds); R2 co 4-dep -> 2+2 (+1 add, wave 4)
//   P3: cg4[0..3] 4-dep -> 2+2 (+4 adds)
// ~9 extra VALU adds/wave/step vs ~60-100 cyc of chain latency removed.
// Everything else identical to r14: 3 raw lgkm-only barriers/step, no-qsel
// duplication (real row = (lane>>2)&3), DPP reduce-scatter, reg-resident
// weights, per-lane dW register pipeline, fW3 col remap, R2 after dst writes.
// ---------------------------------------------------------------------------

typedef _Float16 half8 __attribute__((ext_vector_type(8)));
typedef float floatx4 __attribute__((ext_vector_type(4)));

// ws layout: f16 region (offsets in _Float16 units)
#define H_FW1 0        // [128][64]
#define H_GW1 8192     // [128][64]
#define H_FW2 16384    // [128][128]
#define H_GW2 32768    // [128][128]
#define H_FW3 49152    // [64][128]
#define H_GW3 57344    // [512][128]
#define H_RW1 122880   // [128][64]
#define H_RW2 131072   // [16][128]  (f16 readout weights, transposed)
#define H_TOTAL 133120
// f32 region (offsets in float units from ws base; starts right after f16)
#define F_EMBT 66560             // [64][32]
#define F_W1R0F (F_EMBT + 2048)  // [128]
#define F_W1R0G (F_W1R0F + 128)  // [128]
#define F_CNT 2304
#define PREP_TOTAL (H_TOTAL + F_CNT)

__global__ void prep_kernel(const float* __restrict__ fW1, const float* __restrict__ gW1,
                            const float* __restrict__ fW2, const float* __restrict__ gW2,
                            const float* __restrict__ fW3, const float* __restrict__ gW3,
                            const float* __restrict__ rW1, const float* __restrict__ rW2,
                            const float* __restrict__ embW, void* __restrict__ ws) {
  int idx = blockIdx.x * blockDim.x + threadIdx.x;
  if (idx >= PREP_TOTAL) return;
  if (idx < H_TOTAL) {
    float v;
    if (idx < H_GW1) {
      int t = idx; int c = t >> 6, k = t & 63; v = fW1[(k + 1) * 128 + c];
    } else if (idx < H_FW2) {
      int t = idx - H_GW1; int c = t >> 6, k = t & 63; v = gW1[(k + 1) * 128 + c];
    } else if (idx < H_GW2) {
      int t = idx - H_FW2; int c = t >> 7, k = t & 127; v = fW2[k * 128 + c];
    } else if (idx < H_FW3) {
      int t = idx - H_GW2; int c = t >> 7, k = t & 127; v = gW2[k * 128 + c];
    } else if (idx < H_GW3) {
      int t = idx - H_FW3; int c = t >> 7, k = t & 127; v = fW3[k * 64 + c];
    } else if (idx < H_RW1) {
      int t = idx - H_GW3; int c = t >> 7, k = t & 127; v = gW3[k * 512 + c];
    } else if (idx < H_RW2) {
      int t = idx - H_RW1; int c = t >> 6, k = t & 63; v = rW1[k * 128 + c];
    } else {
      int t = idx - H_RW2; int c = t >> 7, k = t & 127; v = rW2[k * 16 + c];
    }
    ((_Float16*)ws)[idx] = (_Float16)v;
  } else {
    int f = idx - H_TOTAL;
    float v;
    if (f < 2048) {
      int c = f >> 5, k = f & 31; v = embW[k * 64 + c];
      ((float*)ws)[F_EMBT + f] = v;
    } else if (f < 2176) {
      ((float*)ws)[F_W1R0F + (f - 2048)] = fW1[f - 2048];
    } else {
      ((float*)ws)[F_W1R0G + (f - 2176)] = gW1[f - 2176];
    }
  }
}

__device__ __forceinline__ float sp(float x) { return __logf(1.f + __expf(x)); }

// clamp-free tanh: exp(2x)->inf gives 1-0=1; exp(2x)->0 gives 1-2=-1.
__device__ __forceinline__ float ftanh(float x) {
  float e = __expf(2.f * x);
  return 1.f - __fdividef(2.f, e + 1.f);
}

__device__ __forceinline__ floatx4 mfma16(half8 a, half8 b, floatx4 c) {
  return __builtin_amdgcn_mfma_f32_16x16x32_f16(a, b, c, 0, 0, 0);
}

// lane-linear A-layout with sub-k bank shift.
// element (m,k): seg(k>>5)*512 + subk*128 + (subk&1)*32 + m*8 + (k&7)
__device__ __forceinline__ int aofs2(int m, int k) {
  int subk = (k >> 3) & 3;
  return ((k >> 5) << 9) + (subk << 7) + ((subk & 1) << 5) + (m << 3) + (k & 7);
}

// DPP lane-permute mov (VALU pipe; no LDS). CTRL: 0xB1=xor1 (quad_perm
// [1,0,3,2]), 0x4E=xor2 ([2,3,0,1]), 0x141=row_half_mirror (l <-> 7-l
// within each aligned 8-lane group).
template <int CTRL>
__device__ __forceinline__ float dppmov(float v) {
  return __builtin_bit_cast(float,
      __builtin_amdgcn_update_dpp(0, __builtin_bit_cast(int, v), CTRL, 0xF, 0xF, true));
}

// Raw phase barrier: LDS-ordering only; vmcnt left in flight on purpose.
#define BAR()                                                    \
  do {                                                           \
    asm volatile("s_waitcnt lgkmcnt(0)" ::: "memory");           \
    __builtin_amdgcn_s_barrier();                                \
    asm volatile("" ::: "memory");                               \
  } while (0)

__global__ __launch_bounds__(512, 2)
void sde_main(const float* __restrict__ init_noise, const float* __restrict__ dw_noise,
              const float* __restrict__ emb_b,
              const float* __restrict__ f_b1, const float* __restrict__ f_b2,
              const float* __restrict__ f_b3, const float* __restrict__ g_b1,
              const float* __restrict__ g_b2, const float* __restrict__ g_b3,
              const float* __restrict__ r_b1, const float* __restrict__ r_b2,
              const void* __restrict__ ws, float* __restrict__ out_full,
              float* __restrict__ out_match) {
  // lane-linear f16 activation buffers (rows 0-3 real, duplicated reads)
  __shared__ __align__(16) _Float16 zseg[1024];                 // z, K=64
  __shared__ __align__(16) _Float16 h1f[2048], h1g[2048];       // K=128
  __shared__ __align__(16) _Float16 h2f[2048], h2g[2048];
  __shared__ __align__(16) _Float16 hrsg[2048];                 // readout hidden (f16)
  // f32 scratch (pre-loop staging only)
  __shared__ __align__(16) float zb[4 * 68];      // z0 staging
  __shared__ __align__(16) float stg[4 * 36];     // init_noise staging

  const int tid = threadIdx.x;
  const int w = tid >> 6;          // wave 0..7
  const int lane = tid & 63;
  const int ln16 = lane & 15;
  const int quad = lane >> 4;
  const int koff = quad * 8;
  const int wm = w & 3;
  const int b4 = blockIdx.x << 2;
  const _Float16* wsh = (const _Float16*)ws;
  const float* wsf = (const float*)ws;

  const float DTI = 1.0f / 511.0f;
  const float SDT = sqrtf(DTI);

  // ---- step-invariant per-lane constants (registers) ----
  const int col1 = w * 16 + ln16;                 // P1/R1 column
  const float b1fv = f_b1[col1], b1gv = g_b1[col1];
  const float w1fv = wsf[F_W1R0F + col1], w1gv = wsf[F_W1R0G + col1];
  const float rb1v = r_b1[col1];
  const int colA = wm * 32 + ln16, colB = colA + 16;  // P2 columns
  const float* bsrc2 = (w < 4) ? f_b2 : g_b2;
  const float b2vA = bsrc2[colA], b2vB = bsrc2[colB];
  // duplicated A-read offset: MFMA row r <- real row r>>2  =>  all 4 C regs
  // of a lane hold real row `quad` (c[0] usable everywhere, no qsel).
  const int ra = ((lane >> 4) << 7) + (((lane >> 4) & 1) << 5) + (((lane >> 2) & 3) << 3);
  // write addresses
  const int haddr1 = aofs2(quad, col1);
  const int haddr2A = aofs2(quad, colA), haddr2B = aofs2(quad, colB);
  // P3 z-update constants
  const int n8 = ln16 & 7;                   // noise index for this lane
  const int hlf = ln16 >> 3;                 // which half of the 16-group
  const bool writer = ((n8 & 1) == hlf);     // owner of z(quad, lstar)
  const int lstar = (w << 3) + n8;           // owned z column
  const int zwaddr = aofs2(quad, lstar);
  const int fcol = (w << 3) + n8;            // fW3 column (cols 8w..8w+7, x2)
  const float fb3v = f_b3[fcol];
  const float gb0 = g_b3[w * 64 + 0 * 16 + ln16];
  const float gb1 = g_b3[w * 64 + 1 * 16 + ln16];
  const float gb2 = g_b3[w * 64 + 2 * 16 + ln16];
  const float gb3v = g_b3[w * 64 + 3 * 16 + ln16];
  // per-lane dW source offset: dW[row=quad][n=n8]
  const int dwofs_g = (b4 + quad) * 8 + n8;
  // R2-MFMA constants (wave 4): lane (quad,ln16) stores row quad, dim ln16
  const float rb2v = r_b2[ln16];
  const size_t ofull4 = ((size_t)(b4 + quad) * 512) * 16 + ln16;
  const size_t omatch4 = ((size_t)(b4 + quad) * 64) * 16 + ln16;

  // ---- init: stage init_noise (f32) ----
  if (tid < 128) stg[(tid >> 5) * 36 + (tid & 31)] = init_noise[b4 * 32 + tid];

  // ---- persistent B-fragments (VGPR/AGPR-resident for all 511 steps) ----
  // U3: fW3 cols 8w..8w+7 duplicated (P3); R2W: rW2 tile (wave 4, P2/final)
  half8 Bf1[2], Bg1[2], Br1[2], B2[2][4], B3g[4][4], U3[4], R2W[4];
#pragma unroll
  for (int kf = 0; kf < 2; ++kf) {
    Bf1[kf] = *(const half8*)(wsh + H_FW1 + col1 * 64 + kf * 32 + koff);
    Bg1[kf] = *(const half8*)(wsh + H_GW1 + col1 * 64 + kf * 32 + koff);
    Br1[kf] = *(const half8*)(wsh + H_RW1 + col1 * 64 + kf * 32 + koff);
  }
  const _Float16* w2b = wsh + (w < 4 ? H_FW2 : H_GW2);
#pragma unroll
  for (int i2 = 0; i2 < 2; ++i2)
#pragma unroll
    for (int kf = 0; kf < 4; ++kf)
      B2[i2][kf] = *(const half8*)(w2b + ((wm * 2 + i2) * 16 + ln16) * 128 + kf * 32 + koff);
#pragma unroll
  for (int i2 = 0; i2 < 4; ++i2)
#pragma unroll
    for (int kf = 0; kf < 4; ++kf)
      B3g[i2][kf] = *(const half8*)(wsh + H_GW3 + ((w * 4 + i2) * 16 + ln16) * 128 + kf * 32 + koff);
#pragma unroll
  for (int kf = 0; kf < 4; ++kf) {
    U3[kf] = *(const half8*)(wsh + H_FW3 + fcol * 128 + kf * 32 + koff);
    R2W[kf] = *(const half8*)(wsh + H_RW2 + ln16 * 128 + kf * 32 + koff);
  }
  __syncthreads();

  // ---- z0 = init_noise @ emb_W + emb_b ----
  if (tid < 256) {
    const int rr = tid & 3, l = tid >> 2;
    const float* pe = wsf + F_EMBT + l * 32;
    float acc = emb_b[l];
#pragma unroll
    for (int c = 0; c < 8; ++c) {
      float4 a = *(const float4*)(&stg[rr * 36 + 4 * c]);
      float4 v = *(const float4*)(pe + 4 * c);
      acc += a.x * v.x + a.y * v.y + a.z * v.z + a.w * v.w;
    }
    zb[rr * 68 + l] = acc;
    zseg[aofs2(rr, l)] = (_Float16)acc;
  }
  __syncthreads();

  // z f32 state lives in the owner lane's register
  float zreg = writer ? zb[quad * 68 + lstar] : 0.f;

  // per-lane dW register pipeline: dwv = step i's weight (incl. SDT)
  float dwv = dw_noise[dwofs_g] * SDT;
  float dwn = 0.f;

#pragma unroll 1
  for (int i = 0; i < 511; ++i) {
    const float t_s = (float)i * DTI;

    // ---- P1: L1 (f,g) + R1, all chains 1+1 split; issue dW(i+1) load ----
    {
      half8 a0 = *(const half8*)(&zseg[ra]);
      half8 a1 = *(const half8*)(&zseg[512 + ra]);
      {
        int ip = (i < 510) ? i + 1 : 510;
        dwn = dw_noise[(size_t)ip * 8192 + dwofs_g];
      }
      floatx4 zz = {0.f, 0.f, 0.f, 0.f};
      floatx4 cfa = mfma16(a0, Bf1[0], zz), cfb = mfma16(a1, Bf1[1], zz);
      floatx4 cga = mfma16(a0, Bg1[0], zz), cgb = mfma16(a1, Bg1[1], zz);
      floatx4 cra = mfma16(a0, Br1[0], zz), crb = mfma16(a1, Br1[1], zz);
      h1f[haddr1] = (_Float16)sp(cfa[0] + cfb[0] + b1fv + t_s * w1fv);
      h1g[haddr1] = (_Float16)sp(cga[0] + cgb[0] + b1gv + t_s * w1gv);
      hrsg[haddr1] = (_Float16)fmaxf(cra[0] + crb[0] + rb1v, 0.f);
    }
    BAR();

    // ---- P2: L2, chains 2+2 split; R2-MFMA (wave 4, 2+2) after dst writes ----
    {
      const _Float16* asrc = (w < 4) ? h1f : h1g;
      half8 a[4];
#pragma unroll
      for (int s = 0; s < 4; ++s) a[s] = *(const half8*)(&asrc[s * 512 + ra]);
      floatx4 zz = {0.f, 0.f, 0.f, 0.f};
      floatx4 c0a = mfma16(a[0], B2[0][0], zz);
      c0a = mfma16(a[1], B2[0][1], c0a);
      floatx4 c0b = mfma16(a[2], B2[0][2], zz);
      c0b = mfma16(a[3], B2[0][3], c0b);
      floatx4 c1a = mfma16(a[0], B2[1][0], zz);
      c1a = mfma16(a[1], B2[1][1], c1a);
      floatx4 c1b = mfma16(a[2], B2[1][2], zz);
      c1b = mfma16(a[3], B2[1][3], c1b);
      _Float16* dst = (w < 4) ? h2f : h2g;
      dst[haddr2A] = (_Float16)sp(c0a[0] + c0b[0] + b2vA);
      dst[haddr2B] = (_Float16)sp(c1a[0] + c1b[0] + b2vB);
      if (w == 4) {  // after the barrier-gating writes: trails into the wait
        half8 hr[4];
#pragma unroll
        for (int s = 0; s < 4; ++s) hr[s] = *(const half8*)(&hrsg[s * 512 + ra]);
        floatx4 coa = mfma16(hr[0], R2W[0], zz);
        coa = mfma16(hr[1], R2W[1], coa);
        floatx4 cob = mfma16(hr[2], R2W[2], zz);
        cob = mfma16(hr[3], R2W[3], cob);
        float v = coa[0] + cob[0] + rb2v;
        out_full[ofull4 + (size_t)i * 16] = v;
        if ((i & 7) == 0) out_match[omatch4 + (size_t)(i >> 3) * 16] = v;
      }
    }
    BAR();

    // ---- P3: L3 f first (1+1), L3 g (2+2 x4), fused z-update ----
    {
      // f-chain: two independent 2-MFMA chains, issued first
      floatx4 zz = {0.f, 0.f, 0.f, 0.f};
      floatx4 cfa, cfb;
      {
        half8 af0 = *(const half8*)(&h2f[0 * 512 + ra]);
        half8 af1 = *(const half8*)(&h2f[1 * 512 + ra]);
        half8 af2 = *(const half8*)(&h2f[2 * 512 + ra]);
        half8 af3 = *(const half8*)(&h2f[3 * 512 + ra]);
        cfa = mfma16(af0, U3[0], zz); cfa = mfma16(af1, U3[1], cfa);
        cfb = mfma16(af2, U3[2], zz); cfb = mfma16(af3, U3[3], cfb);
      }
      half8 ag[4];
#pragma unroll
      for (int s = 0; s < 4; ++s) ag[s] = *(const half8*)(&h2g[s * 512 + ra]);
      // g-chains: each i2 split 2+2 into independent accumulators
      floatx4 ga[4], gb[4];
#pragma unroll
      for (int i2 = 0; i2 < 4; ++i2) {
        ga[i2] = mfma16(ag[0], B3g[i2][0], zz);
        gb[i2] = mfma16(ag[2], B3g[i2][2], zz);
      }
#pragma unroll
      for (int i2 = 0; i2 < 4; ++i2) {
        ga[i2] = mfma16(ag[1], B3g[i2][1], ga[i2]);
        gb[i2] = mfma16(ag[3], B3g[i2][3], gb[i2]);
      }
      // f-term on VALU while g-MFMAs execute (independent pipes)
      float ft = ftanh(cfa[0] + cfb[0] + fb3v) * DTI;
      // weighted g-terms, one per i2 (dwv = dW[quad][n8]*SDT, register)
      float v0 = ftanh(ga[0][0] + gb[0][0] + gb0) * dwv;
      float v1 = ftanh(ga[1][0] + gb[1][0] + gb1) * dwv;
      float v2 = ftanh(ga[2][0] + gb[2][0] + gb2) * dwv;
      float v3 = ftanh(ga[3][0] + gb[3][0] + gb3v) * dwv;
      // DPP reduce-scatter over 8-lane group (VALU-only, no LDS):
      float s0 = (n8 & 4) ? v0 : v2;
      float s1 = (n8 & 4) ? v1 : v3;
      float pa = ((n8 & 4) ? v2 : v0) + dppmov<0x141>(s0);
      float pb = ((n8 & 4) ? v3 : v1) + dppmov<0x141>(s1);
      float u = (n8 & 2) ? pa : pb;
      float sv = ((n8 & 2) ? pb : pa) + dppmov<0x4E>(u);
      float S = sv + dppmov<0xB1>(sv);
      if (writer) {
        zreg += S + ft;
        zseg[zwaddr] = (_Float16)zreg;
      }
    }
    BAR();

    dwv = dwn * SDT;  // step i+1's weight (load issued back in P1, hidden)
  }

  // ---- final readout T=511 ----
  {
    half8 a0 = *(const half8*)(&zseg[ra]);
    half8 a1 = *(const half8*)(&zseg[512 + ra]);
    floatx4 zz = {0.f, 0.f, 0.f, 0.f};
    floatx4 cra = mfma16(a0, Br1[0], zz), crb = mfma16(a1, Br1[1], zz);
    hrsg[haddr1] = (_Float16)fmaxf(cra[0] + crb[0] + rb1v, 0.f);
  }
  BAR();
  if (w == 4) {
    half8 hr[4];
#pragma unroll
    for (int s = 0; s < 4; ++s) hr[s] = *(const half8*)(&hrsg[s * 512 + ra]);
    floatx4 zz = {0.f, 0.f, 0.f, 0.f};
    floatx4 coa = mfma16(hr[0], R2W[0], zz);
    coa = mfma16(hr[1], R2W[1], coa);
    floatx4 cob = mfma16(hr[2], R2W[2], zz);
    cob = mfma16(hr[3], R2W[3], cob);
    float v = coa[0] + cob[0] + rb2v;
    out_full[ofull4 + (size_t)511 * 16] = v;
  }
}

extern "C" void kernel_launch(void* const* d_in, const int* in_sizes, int n_in,
                              void* d_out, int out_size, void* d_ws, size_t ws_size,
                              hipStream_t stream) {
  (void)in_sizes; (void)n_in; (void)out_size; (void)ws_size;
  const float* init_noise = (const float*)d_in[0];
  const float* dw_noise   = (const float*)d_in[1];
  const float* emb_W      = (const float*)d_in[3];
  const float* emb_b      = (const float*)d_in[4];
  const float* f_W1       = (const float*)d_in[5];
  const float* f_b1       = (const float*)d_in[6];
  const float* f_W2       = (const float*)d_in[7];
  const float* f_b2       = (const float*)d_in[8];
  const float* f_W3       = (const float*)d_in[9];
  const float* f_b3       = (const float*)d_in[10];
  const float* g_W1       = (const float*)d_in[11];
  const float* g_b1       = (const float*)d_in[12];
  const float* g_W2       = (const float*)d_in[13];
  const float* g_b2       = (const float*)d_in[14];
  const float* g_W3       = (const float*)d_in[15];
  const float* g_b3       = (const float*)d_in[16];
  const float* r_W1       = (const float*)d_in[17];
  const float* r_b1       = (const float*)d_in[18];
  const float* r_W2       = (const float*)d_in[19];
  const float* r_b2       = (const float*)d_in[20];
  float* out_full = (float*)d_out;
  float* out_match = out_full + (size_t)1024 * 512 * 16;

  hipLaunchKernelGGL(prep_kernel, dim3((PREP_TOTAL + 255) / 256), dim3(256), 0, stream,
                     f_W1, g_W1, f_W2, g_W2, f_W3, g_W3, r_W1, r_W2, emb_W, d_ws);
  hipLaunchKernelGGL(sde_main, dim3(256), dim3(512), 0, stream,
                     init_noise, dw_noise, emb_b, f_b1, f_b2, f_b3,
                     g_b1, g_b2, g_b3, r_b1, r_b2, d_ws, out_full, out_match);
}